// Round 3
// baseline (521.864 us; speedup 1.0000x reference)
//
#include <hip/hip_runtime.h>

typedef unsigned short u16;
typedef unsigned int u32;
typedef __bf16 bf16x8 __attribute__((ext_vector_type(8)));
typedef float f32x4 __attribute__((ext_vector_type(4)));
typedef int i32x4 __attribute__((ext_vector_type(4)));

#define BATCH 8
#define CH 96
#define HH 128
#define WW 128
#define HWSZ 16384

// ---- workspace layout (bytes), hand-aliased by lifetime ----
// timeline: trans -> convqk -> convv -> patch -> gprep -> attn -> softmax -> fcfr2 -> final
#define OFF_FQ    0ULL           // f32 NHWC [B][H][W][C] 48MiB   (convqk .. attn)
#define OFF_FK    50331648ULL    // f32 NHWC -> Ktilde in place    (convqk .. attn)
#define OFF_IN1H  100663296ULL   // bf16 NHWC 24MiB (trans .. convqk)
#define OFF_F1W   100663296ULL   //   then: bf16 NHWC F1tilde (patch .. fcfr2)
#define OFF_IN1L  125829120ULL   // bf16 NHWC (trans .. convqk)
#define OFF_GT    125829120ULL   //   then: bf16 [B][C][x][y] (gprep .. final)
#define OFF_IN2   150994944ULL   // bf16 NHWC (trans .. convv)
#define OFF_PART  150994944ULL   //   then: f32 [B][64][96][96] 18MiB (attn .. softmax)
#define OFF_FVB   176160768ULL   // bf16 NHWC (convv .. gprep)
#define OFF_FCFR  176160768ULL   //   then: bf16 [B][C][y][x] (fcfr2 .. final)
#define OFF_FVN   201326592ULL   // bf16 [B][C][y][x] (gprep .. final)
#define OFF_ATTNB 226492416ULL   // bf16 [B][96][96] 147456 (softmax .. fcfr2)
#define OFF_WQH   226639872ULL   // bf16 [9][96][96] each 165888
#define OFF_WQL   (OFF_WQH + 165888ULL)
#define OFF_WKH   (OFF_WQL + 165888ULL)
#define OFF_WKL   (OFF_WKH + 165888ULL)
#define OFF_WV    (OFF_WKL + 165888ULL)
#define WS_NEED   (OFF_WV + 165888ULL)   // 227,469,312 bytes (~217 MiB)

__device__ __forceinline__ u16 f2bf(float f) {
    u32 u = __builtin_bit_cast(u32, f);
    u += 0x7fffu + ((u >> 16) & 1u);
    return (u16)(u >> 16);
}
__device__ __forceinline__ float bf2f(u16 h) {
    u32 u = ((u32)h) << 16;
    return __builtin_bit_cast(float, u);
}
__device__ __forceinline__ f32x4 mfma16(i32x4 a, i32x4 b, f32x4 c) {
    return __builtin_amdgcn_mfma_f32_16x16x32_bf16(
        __builtin_bit_cast(bf16x8, a), __builtin_bit_cast(bf16x8, b), c, 0, 0, 0);
}

// ---- diagnostic: report ws_size (KiB) through absmax ----
__global__ __launch_bounds__(256) void k_diag(float* __restrict__ out, int n, float val) {
    for (int i = blockIdx.x * 256 + threadIdx.x; i < n; i += gridDim.x * 256) out[i] = val;
}

// ---- NCHW f32 -> NHWC bf16 (hi[, lo]) ----
__global__ __launch_bounds__(256) void k_trans_split(const float* __restrict__ src,
        u16* __restrict__ dh, u16* __restrict__ dl) {
    __shared__ float tile[96][129];
    int blk = blockIdx.x;
    int b = blk >> 7, y = blk & 127;
    const float* s = src + (size_t)b * CH * HWSZ + (size_t)y * WW;
    for (int idx = threadIdx.x; idx < CH * WW; idx += 256) {
        int c = idx >> 7, x = idx & 127;
        tile[c][x] = s[(size_t)c * HWSZ + x];
    }
    __syncthreads();
    size_t obase = ((size_t)(b * HH + y)) * WW * CH;
    for (int idx = threadIdx.x; idx < WW * CH; idx += 256) {
        int x = idx / CH, c = idx - (idx / CH) * CH;
        float v = tile[c][x];
        u16 h = f2bf(v);
        dh[obase + idx] = h;
        if (dl) dl[obase + idx] = f2bf(v - bf2f(h));
    }
}

// ---- weights [co][ci][3][3] f32 -> [tap][co][ci] bf16 (hi[, lo]) ----
__global__ __launch_bounds__(128) void k_weights(const float* __restrict__ w,
        u16* __restrict__ dh, u16* __restrict__ dl) {
    int co = blockIdx.x;
    for (int idx = threadIdx.x; idx < 9 * CH; idx += 128) {
        int tap = idx / CH, ci = idx - tap * CH;
        float v = w[((size_t)co * CH + ci) * 9 + tap];
        u16 h = f2bf(v);
        size_t o = ((size_t)tap * CH + co) * CH + ci;
        dh[o] = h;
        if (dl) dl[o] = f2bf(v - bf2f(h));
    }
}

// ---- fused Q+K conv, split-bf16 (3 MFMA per term): out NHWC f32 ----
__global__ __launch_bounds__(256) void k_convqk(
        const u16* __restrict__ inh, const u16* __restrict__ inl,
        const u16* __restrict__ wqh, const u16* __restrict__ wql,
        const u16* __restrict__ wkh, const u16* __restrict__ wkl,
        const float* __restrict__ bq, const float* __restrict__ bk,
        float* __restrict__ fq, float* __restrict__ fk) {
    int blk = blockIdx.x;
    int b = blk >> 8, y = (blk >> 1) & 127, x0 = (blk & 1) << 6;
    int lane = threadIdx.x & 63, wv_ = threadIdx.x >> 6;
    int l15 = lane & 15, g = lane >> 4;
    f32x4 acc[4][3];
#pragma unroll
    for (int mf = 0; mf < 4; mf++)
#pragma unroll
        for (int f = 0; f < 3; f++) acc[mf][f] = (f32x4){0.f, 0.f, 0.f, 0.f};

    for (int cic = 0; cic < 3; cic++) {
        int ci0 = cic * 32 + g * 8;
#pragma unroll
        for (int tap = 0; tap < 9; tap++) {
            int dy = tap / 3 - 1, dx = tap % 3 - 1;
            int yy = y + dy;
            bool rowok = ((unsigned)yy < 128u);
            i32x4 ah[4], al[4];
#pragma unroll
            for (int mf = 0; mf < 4; mf++) {
                int xx = x0 + mf * 16 + l15 + dx;
                i32x4 vh = {0, 0, 0, 0}, vl = {0, 0, 0, 0};
                if (rowok && ((unsigned)xx < 128u)) {
                    size_t e = ((size_t)(((b * 128 + yy) * 128 + xx) * 96 + ci0)) >> 3;
                    vh = ((const i32x4*)inh)[e];
                    vl = ((const i32x4*)inl)[e];
                }
                ah[mf] = vh; al[mf] = vl;
            }
#pragma unroll
            for (int f = 0; f < 3; f++) {
                int n0 = wv_ * 48 + f * 16;
                const u16* WH = (n0 < 96) ? wqh : wkh;
                const u16* WL = (n0 < 96) ? wql : wkl;
                int co = ((n0 < 96) ? n0 : n0 - 96) + l15;
                size_t we = ((size_t)((tap * 96 + co) * 96 + ci0)) >> 3;
                i32x4 bh = ((const i32x4*)WH)[we];
                i32x4 bl = ((const i32x4*)WL)[we];
#pragma unroll
                for (int mf = 0; mf < 4; mf++) {
                    acc[mf][f] = mfma16(ah[mf], bh, acc[mf][f]);
                    acc[mf][f] = mfma16(ah[mf], bl, acc[mf][f]);
                    acc[mf][f] = mfma16(al[mf], bh, acc[mf][f]);
                }
            }
        }
    }
#pragma unroll
    for (int f = 0; f < 3; f++) {
        int n0 = wv_ * 48 + f * 16;
        bool isQ = (n0 < 96);
        float* outp = isQ ? fq : fk;
        const float* bias = isQ ? bq : bk;
        int co = (isQ ? n0 : n0 - 96) + l15;
        float bb = bias[co];
#pragma unroll
        for (int mf = 0; mf < 4; mf++)
#pragma unroll
            for (int r = 0; r < 4; r++) {
                int xp = x0 + mf * 16 + g * 4 + r;
                outp[((size_t)((b * 128 + y) * 128 + xp)) * 96 + co] = acc[mf][f][r] + bb;
            }
    }
}

// ---- V conv, single bf16: out NHWC bf16 ----
__global__ __launch_bounds__(256) void k_convv(
        const u16* __restrict__ inb, const u16* __restrict__ wvh,
        const float* __restrict__ bvv, u16* __restrict__ fvb) {
    int blk = blockIdx.x;
    int b = blk >> 7, y = blk & 127;
    int lane = threadIdx.x & 63, wv_ = threadIdx.x >> 6;
    int l15 = lane & 15, g = lane >> 4;
    int x0 = (wv_ >> 1) * 64;
    int co0b = (wv_ & 1) * 48;
    f32x4 acc[4][3];
#pragma unroll
    for (int mf = 0; mf < 4; mf++)
#pragma unroll
        for (int f = 0; f < 3; f++) acc[mf][f] = (f32x4){0.f, 0.f, 0.f, 0.f};

    for (int cic = 0; cic < 3; cic++) {
        int ci0 = cic * 32 + g * 8;
#pragma unroll
        for (int tap = 0; tap < 9; tap++) {
            int dy = tap / 3 - 1, dx = tap % 3 - 1;
            int yy = y + dy;
            bool rowok = ((unsigned)yy < 128u);
            i32x4 ah[4];
#pragma unroll
            for (int mf = 0; mf < 4; mf++) {
                int xx = x0 + mf * 16 + l15 + dx;
                i32x4 v = {0, 0, 0, 0};
                if (rowok && ((unsigned)xx < 128u))
                    v = ((const i32x4*)inb)[((size_t)(((b * 128 + yy) * 128 + xx) * 96 + ci0)) >> 3];
                ah[mf] = v;
            }
#pragma unroll
            for (int f = 0; f < 3; f++) {
                int co = co0b + f * 16 + l15;
                i32x4 bfr = ((const i32x4*)wvh)[((size_t)((tap * 96 + co) * 96 + ci0)) >> 3];
#pragma unroll
                for (int mf = 0; mf < 4; mf++)
                    acc[mf][f] = mfma16(ah[mf], bfr, acc[mf][f]);
            }
        }
    }
#pragma unroll
    for (int f = 0; f < 3; f++) {
        int co = co0b + f * 16 + l15;
        float bb = bvv[co];
#pragma unroll
        for (int mf = 0; mf < 4; mf++)
#pragma unroll
            for (int r = 0; r < 4; r++) {
                int xp = x0 + mf * 16 + g * 4 + r;
                fvb[((size_t)((b * 128 + y) * 128 + xp)) * 96 + co] = f2bf(acc[mf][f][r] + bb);
            }
    }
}

// ---- per-patch: FK -> Ktilde = M B M (in place); F1W = A M B (bf16 NHWC) ----
// M = D^T D = 8I + 2*ones  =>  MBM = 64B + 16(rowsumB_r + colsumB_c) + 4*totB
//                              AMB = 8 A@B + 2 rsA_r * csB_c
__global__ __launch_bounds__(256) void k_patch(
        const float* __restrict__ fq, float* __restrict__ fk, u16* __restrict__ f1w) {
    int blk = blockIdx.x;
    int b = blk >> 6, py = (blk >> 1) & 31, xh = blk & 1;
    int y0 = py * 4;
    // 16 patches (xh half of 32) * 96 channels = 1536 items, 6 iters
    for (int it = 0; it < 6; it++) {
        int item = threadIdx.x + it * 256;
        int pxl = item / 96, c = item - pxl * 96;
        int px = xh * 16 + pxl;
        int x0 = px * 4;
        float A[4][4], Bm[4][4];
        size_t rb[4];
#pragma unroll
        for (int r = 0; r < 4; r++) {
            rb[r] = ((size_t)((b * 128 + y0 + r) * 128 + x0)) * 96 + c;
#pragma unroll
            for (int m = 0; m < 4; m++) {
                A[r][m] = fq[rb[r] + (size_t)m * 96];
                Bm[r][m] = fk[rb[r] + (size_t)m * 96];
            }
        }
        float rsB[4], csB[4], rsA[4], tot = 0.f;
#pragma unroll
        for (int r = 0; r < 4; r++) {
            rsB[r] = Bm[r][0] + Bm[r][1] + Bm[r][2] + Bm[r][3];
            rsA[r] = A[r][0] + A[r][1] + A[r][2] + A[r][3];
            tot += rsB[r];
        }
#pragma unroll
        for (int m = 0; m < 4; m++) csB[m] = Bm[0][m] + Bm[1][m] + Bm[2][m] + Bm[3][m];
        // Ktilde in place
#pragma unroll
        for (int r = 0; r < 4; r++)
#pragma unroll
            for (int m = 0; m < 4; m++)
                fk[rb[r] + (size_t)m * 96] = 64.f * Bm[r][m] + 16.f * (rsB[r] + csB[m]) + 4.f * tot;
        // F1tilde -> bf16 NHWC
#pragma unroll
        for (int r = 0; r < 4; r++)
#pragma unroll
            for (int m = 0; m < 4; m++) {
                float ab = A[r][0] * Bm[0][m] + A[r][1] * Bm[1][m]
                         + A[r][2] * Bm[2][m] + A[r][3] * Bm[3][m];
                f1w[rb[r] + (size_t)m * 96] = f2bf(8.f * ab + 2.f * rsA[r] * csB[m]);
            }
    }
}

// ---- Gt[b][c][x][y] = (F_Q - 0.5 F_V)(y,x) bf16 ; Fvn[b][c][y][x] = F_V bf16 ----
__global__ __launch_bounds__(256) void k_gprep(
        const float* __restrict__ fqn, const u16* __restrict__ fvb,
        u16* __restrict__ gt, u16* __restrict__ fvn) {
    __shared__ u16 lg[8 * 32 * 33];
    __shared__ u16 lv[8 * 32 * 33];
    int blk = blockIdx.x;
    int b = blk / 192;
    int r = blk - b * 192;
    int yt = r / 48; r -= yt * 48;
    int xt = r / 12; int cc = r - xt * 12;
    int y0 = yt * 32, x0 = xt * 32, c0 = cc * 8;
    for (int idx = threadIdx.x; idx < 8192; idx += 256) {
        int pix = idx >> 3, cl = idx & 7;
        int yy = pix >> 5, xx = pix & 31;
        size_t off = ((size_t)((b * 128 + y0 + yy) * 128 + x0 + xx)) * 96 + c0 + cl;
        float q = fqn[off];
        float v = bf2f(fvb[off]);
        int la = (cl * 32 + yy) * 33 + xx;
        lg[la] = f2bf(q - 0.5f * v);
        lv[la] = f2bf(v);
    }
    __syncthreads();
    for (int idx = threadIdx.x; idx < 8192; idx += 256) {
        int yy = idx & 31, xl = (idx >> 5) & 31, cl = idx >> 10;
        gt[((size_t)((b * 96 + c0 + cl) * 128 + x0 + xl)) * 128 + y0 + yy] = lg[(cl * 32 + yy) * 33 + xl];
    }
    for (int idx = threadIdx.x; idx < 8192; idx += 256) {
        int xx = idx & 31, yl = (idx >> 5) & 31, cl = idx >> 10;
        fvn[((size_t)((b * 96 + c0 + cl) * 128 + y0 + yl)) * 128 + x0 + xx] = lv[(cl * 32 + yl) * 33 + xx];
    }
}

// ---- attn logits: [96 x 16384] dot [96 x 16384] from NHWC, split over 64 pixel slices.
// f32 inner (64 px) -> f64 master accumulators. PART f32 [B][64][96][96].
__global__ __launch_bounds__(256) void k_attn(
        const float* __restrict__ fq, const float* __restrict__ kt,
        float* __restrict__ part) {
    __shared__ float qs[96 * 65];
    __shared__ float ks[96 * 65];
    int b = blockIdx.x >> 6, s = blockIdx.x & 63;
    int l0 = s * 256;
    int tx = threadIdx.x & 15, ty = threadIdx.x >> 4;
    double accD[6][6];
#pragma unroll
    for (int a = 0; a < 6; a++)
#pragma unroll
        for (int bb = 0; bb < 6; bb++) accD[a][bb] = 0.0;
    for (int ch = 0; ch < 4; ch++) {
        __syncthreads();
        for (int idx = threadIdx.x; idx < 1536; idx += 256) {
            int p = idx / 24, c0 = (idx - p * 24) * 4;
            size_t off = ((size_t)b * 16384 + l0 + ch * 64 + p) * 96 + c0;
            f32x4 qv = *(const f32x4*)(fq + off);
            f32x4 kv = *(const f32x4*)(kt + off);
#pragma unroll
            for (int u = 0; u < 4; u++) {
                qs[(c0 + u) * 65 + p] = qv[u];
                ks[(c0 + u) * 65 + p] = kv[u];
            }
        }
        __syncthreads();
        float acc[6][6];
#pragma unroll
        for (int a = 0; a < 6; a++)
#pragma unroll
            for (int bb = 0; bb < 6; bb++) acc[a][bb] = 0.f;
        for (int l = 0; l < 64; l++) {
            float qv[6], kv[6];
#pragma unroll
            for (int a = 0; a < 6; a++) qv[a] = qs[(ty + 16 * a) * 65 + l];
#pragma unroll
            for (int bb = 0; bb < 6; bb++) kv[bb] = ks[(tx + 16 * bb) * 65 + l];
#pragma unroll
            for (int a = 0; a < 6; a++)
#pragma unroll
                for (int bb = 0; bb < 6; bb++) acc[a][bb] += qv[a] * kv[bb];
        }
#pragma unroll
        for (int a = 0; a < 6; a++)
#pragma unroll
            for (int bb = 0; bb < 6; bb++) accD[a][bb] += (double)acc[a][bb];
    }
#pragma unroll
    for (int a = 0; a < 6; a++)
#pragma unroll
        for (int bb = 0; bb < 6; bb++)
            part[((size_t)((b * 64 + s) * 96 + ty + 16 * a)) * 96 + tx + 16 * bb] = (float)accD[a][bb];
}

// ---- reduce split-K + temperature + row softmax -> bf16 weights ----
__global__ __launch_bounds__(128) void k_softmax(
        const float* __restrict__ part, const float* __restrict__ temp,
        u16* __restrict__ attnb) {
    __shared__ float red[128];
    int bi = blockIdx.x;
    int b = bi / 96, i2 = bi - b * 96;
    int j2 = threadIdx.x;
    float v = 0.f;
    if (j2 < 96) {
        for (int s = 0; s < 64; s++)
            v += part[((size_t)((b * 64 + s) * 96 + i2)) * 96 + j2];
        v *= temp[0];
    }
    red[j2] = (j2 < 96) ? v : -3.4e38f;
    __syncthreads();
    for (int off = 64; off >= 1; off >>= 1) {
        if (j2 < off) red[j2] = fmaxf(red[j2], red[j2 + off]);
        __syncthreads();
    }
    float mx = red[0];
    __syncthreads();
    float e = (j2 < 96) ? expf(v - mx) : 0.f;
    red[j2] = e;
    __syncthreads();
    for (int off = 64; off >= 1; off >>= 1) {
        if (j2 < off) red[j2] += red[j2 + off];
        __syncthreads();
    }
    float sum = red[0];
    if (j2 < 96) attnb[((size_t)(b * 96) + i2) * 96 + j2] = f2bf(e / sum);
}

// ---- FCFR[b][i][pix] = sum_j attn[i][j] * F1W[b][pix][j]  (bf16 MFMA) ----
__global__ __launch_bounds__(256) void k_fcfr2(
        const u16* __restrict__ attnb, const u16* __restrict__ f1w,
        u16* __restrict__ fc) {
    int b = blockIdx.x >> 6, pc = blockIdx.x & 63;
    int lane = threadIdx.x & 63, wv_ = threadIdx.x >> 6;
    int l15 = lane & 15, g = lane >> 4;
    int pbase = pc * 256 + wv_ * 64;
    f32x4 acc[6][4];
#pragma unroll
    for (int m = 0; m < 6; m++)
#pragma unroll
        for (int n = 0; n < 4; n++) acc[m][n] = (f32x4){0.f, 0.f, 0.f, 0.f};
#pragma unroll
    for (int ks = 0; ks < 3; ks++) {
        int k0 = ks * 32 + g * 8;
        i32x4 afr[6];
#pragma unroll
        for (int m = 0; m < 6; m++)
            afr[m] = *(const i32x4*)(attnb + ((size_t)(b * 96 + m * 16 + l15)) * 96 + k0);
#pragma unroll
        for (int n = 0; n < 4; n++) {
            // FIX (round 2): batch offset b*16384 was missing -> batches 1..7 read batch 0's F1W
            i32x4 bfr = *(const i32x4*)(f1w + ((size_t)(b * 16384 + pbase + n * 16 + l15)) * 96 + k0);
#pragma unroll
            for (int m = 0; m < 6; m++)
                acc[m][n] = mfma16(afr[m], bfr, acc[m][n]);
        }
    }
#pragma unroll
    for (int m = 0; m < 6; m++)
#pragma unroll
        for (int n = 0; n < 4; n++)
#pragma unroll
            for (int r = 0; r < 4; r++) {
                int i2 = m * 16 + g * 4 + r;
                int pix = pbase + n * 16 + l15;
                fc[((size_t)(b * 96 + i2)) * HWSZ + pix] = f2bf(acc[m][n][r]);
            }
}

// ---- out = Fcfrout @ (F_Q - 0.5 F_V) + F_V  (bf16 MFMA, per (b,c) 128^3) ----
__global__ __launch_bounds__(256) void k_final(
        const u16* __restrict__ fc, const u16* __restrict__ gt,
        const u16* __restrict__ fvn, float* __restrict__ out) {
    int b = blockIdx.x / 96, c = blockIdx.x - b * 96;
    int lane = threadIdx.x & 63, wv_ = threadIdx.x >> 6;
    int l15 = lane & 15, g = lane >> 4;
    const u16* A = fc + ((size_t)(b * 96 + c)) * HWSZ;   // [y][k=x']
    const u16* Bm = gt + ((size_t)(b * 96 + c)) * HWSZ;  // [x][k=y']
    f32x4 acc[2][8];
#pragma unroll
    for (int mf = 0; mf < 2; mf++)
#pragma unroll
        for (int nf = 0; nf < 8; nf++) acc[mf][nf] = (f32x4){0.f, 0.f, 0.f, 0.f};
#pragma unroll
    for (int kc = 0; kc < 4; kc++) {
        int k0 = kc * 32 + g * 8;
        i32x4 af[2];
#pragma unroll
        for (int mf = 0; mf < 2; mf++)
            af[mf] = *(const i32x4*)(A + (size_t)(wv_ * 32 + mf * 16 + l15) * 128 + k0);
#pragma unroll
        for (int nf = 0; nf < 8; nf++) {
            i32x4 bf = *(const i32x4*)(Bm + (size_t)(nf * 16 + l15) * 128 + k0);
#pragma unroll
            for (int mf = 0; mf < 2; mf++)
                acc[mf][nf] = mfma16(af[mf], bf, acc[mf][nf]);
        }
    }
    const u16* V = fvn + ((size_t)(b * 96 + c)) * HWSZ;  // [y][x]
    float* O = out + ((size_t)(b * 96 + c)) * HWSZ;
#pragma unroll
    for (int mf = 0; mf < 2; mf++)
#pragma unroll
        for (int nf = 0; nf < 8; nf++)
#pragma unroll
            for (int r = 0; r < 4; r++) {
                int y = wv_ * 32 + mf * 16 + g * 4 + r;
                int x = nf * 16 + l15;
                O[y * 128 + x] = acc[mf][nf][r] + bf2f(V[y * 128 + x]);
            }
}

extern "C" void kernel_launch(void* const* d_in, const int* in_sizes, int n_in,
                              void* d_out, int out_size, void* d_ws, size_t ws_size,
                              hipStream_t stream) {
    (void)in_sizes; (void)n_in;
    if (ws_size < (size_t)WS_NEED) {
        // diagnostic: absmax will read ~= ws_size/1024 (KiB)
        k_diag<<<2048, 256, 0, stream>>>((float*)d_out, out_size, (float)(ws_size >> 10));
        return;
    }
    const float* in1 = (const float*)d_in[0];
    const float* in2 = (const float*)d_in[1];
    const float* wq  = (const float*)d_in[2];
    const float* bq  = (const float*)d_in[3];
    const float* wk  = (const float*)d_in[4];
    const float* bk  = (const float*)d_in[5];
    const float* wv  = (const float*)d_in[6];
    const float* bv  = (const float*)d_in[7];
    const float* temp = (const float*)d_in[8];
    char* ws = (char*)d_ws;
    float* FQ   = (float*)(ws + OFF_FQ);
    float* FK   = (float*)(ws + OFF_FK);
    u16*  IN1H  = (u16*)(ws + OFF_IN1H);
    u16*  IN1L  = (u16*)(ws + OFF_IN1L);
    u16*  IN2B  = (u16*)(ws + OFF_IN2);
    u16*  FVB   = (u16*)(ws + OFF_FVB);
    u16*  F1W   = (u16*)(ws + OFF_F1W);
    u16*  GT    = (u16*)(ws + OFF_GT);
    u16*  FVN   = (u16*)(ws + OFF_FVN);
    float* PART = (float*)(ws + OFF_PART);
    u16*  ATTNB = (u16*)(ws + OFF_ATTNB);
    u16*  FCFR  = (u16*)(ws + OFF_FCFR);
    u16*  WQH   = (u16*)(ws + OFF_WQH);
    u16*  WQL   = (u16*)(ws + OFF_WQL);
    u16*  WKH   = (u16*)(ws + OFF_WKH);
    u16*  WKL   = (u16*)(ws + OFF_WKL);
    u16*  WVH   = (u16*)(ws + OFF_WV);

    k_trans_split<<<1024, 256, 0, stream>>>(in1, IN1H, IN1L);
    k_trans_split<<<1024, 256, 0, stream>>>(in2, IN2B, nullptr);
    k_weights<<<96, 128, 0, stream>>>(wq, WQH, WQL);
    k_weights<<<96, 128, 0, stream>>>(wk, WKH, WKL);
    k_weights<<<96, 128, 0, stream>>>(wv, WVH, nullptr);
    k_convqk<<<2048, 256, 0, stream>>>(IN1H, IN1L, WQH, WQL, WKH, WKL, bq, bk, FQ, FK);
    k_convv<<<1024, 256, 0, stream>>>(IN2B, WVH, bv, FVB);
    k_patch<<<512, 256, 0, stream>>>(FQ, FK, F1W);        // FK -> Ktilde in place; F1W over IN1H (dead)
    k_gprep<<<1536, 256, 0, stream>>>(FQ, FVB, GT, FVN);  // GT over IN1L (dead)
    k_attn<<<512, 256, 0, stream>>>(FQ, FK, PART);        // PART over IN2B (dead)
    k_softmax<<<768, 128, 0, stream>>>(PART, temp, ATTNB);
    k_fcfr2<<<512, 256, 0, stream>>>(ATTNB, F1W, FCFR);   // FCFR over FVB (dead)
    k_final<<<768, 256, 0, stream>>>(FCFR, GT, FVN, (float*)d_out);
}

// Round 5
// 405.442 us; speedup vs baseline: 1.2871x; 1.2871x over previous
//
#include <hip/hip_runtime.h>

typedef unsigned short u16;
typedef unsigned int u32;
typedef __bf16 bf16x8 __attribute__((ext_vector_type(8)));
typedef float f32x4 __attribute__((ext_vector_type(4)));
typedef int i32x4 __attribute__((ext_vector_type(4)));

#define BATCH 8
#define CH 96
#define HWSZ 16384
#define PADP (130*130*96)   // elems per padded plane-image

// ---- workspace layout (bytes) ----
// order: zhalo,trans -> weights -> convqk -> convv -> patch -> attn -> softmax -> gprep -> fcfr2 -> final
#define OFF_FQ     0ULL          // f32 NHWC (convqk..gprep)
#define OFF_FK     50331648ULL   // f32 NHWC -> Ktilde (convqk..attn); then:
#define OFF_GT     50331648ULL   //   bf16 [B][C][x][y] (gprep..final)
#define OFF_FVN    75497472ULL   //   bf16 [B][C][y][x] (gprep..final)
#define OFF_PAD1H  100663296ULL  // bf16 padded (trans..convqk) 25958400
#define OFF_F1W    100663296ULL  //   bf16 NHWC F1tilde (patch..fcfr2)
#define OFF_PAD1L  126621696ULL  // bf16 padded (trans..convqk)
#define OFF_PART   126621696ULL  //   f32 [B][64][96][96] (attn..softmax)
#define OFF_PAD2   152580096ULL  // bf16 padded (trans..convv)
#define OFF_FCFR   152580096ULL  //   bf16 [B][C][y][x] (fcfr2..final)
#define OFF_FVB    178538496ULL  // bf16 NHWC (convv..gprep)
#define OFF_ATTNB  203704320ULL  // bf16 [B][96][96]
#define OFF_WQK    203851776ULL  // bf16 packed [27][2][4][192][8] per step: 663552
#define OFF_WV     204515328ULL  // bf16 packed [27][4][96][8]: 165888
#define WS_NEED    204681216ULL

__device__ __forceinline__ u16 f2bf(float f) {
    u32 u = __builtin_bit_cast(u32, f);
    u += 0x7fffu + ((u >> 16) & 1u);
    return (u16)(u >> 16);
}
__device__ __forceinline__ float bf2f(u16 h) {
    u32 u = ((u32)h) << 16;
    return __builtin_bit_cast(float, u);
}
__device__ __forceinline__ f32x4 mfma16(i32x4 a, i32x4 b, f32x4 c) {
    return __builtin_amdgcn_mfma_f32_16x16x32_bf16(
        __builtin_bit_cast(bf16x8, a), __builtin_bit_cast(bf16x8, b), c, 0, 0, 0);
}
__device__ __forceinline__ void gl_lds16(const u16* g, u16* l) {
    __builtin_amdgcn_global_load_lds(
        (const __attribute__((address_space(1))) unsigned int*)g,
        (__attribute__((address_space(3))) unsigned int*)l, 16, 0, 0);
}

__global__ __launch_bounds__(256) void k_diag(float* __restrict__ out, int n, float val) {
    for (int i = blockIdx.x * 256 + threadIdx.x; i < n; i += gridDim.x * 256) out[i] = val;
}

// ---- zero halo of the 3 contiguous padded planes (24 images) ----
__global__ __launch_bounds__(256) void k_zhalo(u16* __restrict__ p) {
    size_t base = (size_t)blockIdx.x * PADP;
    for (int i = threadIdx.x; i < 130 * 96; i += 256) {
        p[base + i] = 0;
        p[base + (size_t)129 * 130 * 96 + i] = 0;
    }
    for (int i = threadIdx.x; i < 128 * 2 * 96; i += 256) {
        int row = i / 192, k = i - row * 192;
        int x = (k < 96) ? 0 : 129, c = (k < 96) ? k : k - 96;
        p[base + ((size_t)(row + 1) * 130 + x) * 96 + c] = 0;
    }
}

// ---- NCHW f32 -> padded NHWC bf16 (hi[, lo]) ----
__global__ __launch_bounds__(256) void k_trans_split(const float* __restrict__ src,
        u16* __restrict__ dh, u16* __restrict__ dl) {
    __shared__ float tile[96][129];
    int b = blockIdx.x >> 7, y = blockIdx.x & 127;
    const float* s = src + (size_t)b * CH * HWSZ + (size_t)y * 128;
    for (int idx = threadIdx.x; idx < CH * 128; idx += 256) {
        int c = idx >> 7, x = idx & 127;
        tile[c][x] = s[(size_t)c * HWSZ + x];
    }
    __syncthreads();
    size_t obase = ((size_t)(b * 130 + y + 1) * 130 + 1) * 96;
    for (int idx = threadIdx.x; idx < 128 * CH; idx += 256) {
        int x = idx / CH, c = idx - x * CH;
        float v = tile[c][x];
        u16 h = f2bf(v);
        dh[obase + idx] = h;
        if (dl) dl[obase + idx] = f2bf(v - bf2f(h));
    }
}

// ---- Q+K weights -> packed [s=cic*9+tap][plane][g][co192][8] bf16 hi/lo ----
__global__ __launch_bounds__(128) void k_weights_qk(const float* __restrict__ wq,
        const float* __restrict__ wk, u16* __restrict__ dst) {
    int co = blockIdx.x;  // 0..191
    const float* w = (co < 96) ? wq : wk;
    int cs = (co < 96) ? co : co - 96;
    for (int idx = threadIdx.x; idx < 864; idx += 128) {
        int tap = idx / 96, ci = idx - tap * 96;
        int cic = ci >> 5, g = (ci >> 3) & 3, c7 = ci & 7;
        float v = w[((size_t)cs * 96 + ci) * 9 + tap];
        u16 h = f2bf(v), lo = f2bf(v - bf2f(h));
        size_t s = (size_t)(cic * 9 + tap);
        dst[(((s * 2 + 0) * 4 + g) * 192 + co) * 8 + c7] = h;
        dst[(((s * 2 + 1) * 4 + g) * 192 + co) * 8 + c7] = lo;
    }
}

// ---- V weights -> packed [s][g][co96][8] bf16 ----
__global__ __launch_bounds__(128) void k_weights_v(const float* __restrict__ wv,
        u16* __restrict__ dst) {
    int co = blockIdx.x;  // 0..95
    for (int idx = threadIdx.x; idx < 864; idx += 128) {
        int tap = idx / 96, ci = idx - tap * 96;
        int cic = ci >> 5, g = (ci >> 3) & 3, c7 = ci & 7;
        float v = wv[((size_t)co * 96 + ci) * 9 + tap];
        size_t s = (size_t)(cic * 9 + tap);
        dst[((s * 4 + g) * 96 + co) * 8 + c7] = f2bf(v);
    }
}

// ---- fused Q+K conv, split-bf16, LDS-staged weights, padded input ----
__global__ __launch_bounds__(256, 3) void k_convqk2(
        const u16* __restrict__ ph, const u16* __restrict__ pl,
        const u16* __restrict__ wqk,
        const float* __restrict__ bq, const float* __restrict__ bk,
        float* __restrict__ fq, float* __restrict__ fk) {
    __shared__ u16 wbuf[2][12288];  // [plane][g][co192][8] per buffer, 24KB each
    const int tid = threadIdx.x;
    const int b = blockIdx.x >> 7, y = blockIdx.x & 127;
    const int w = tid >> 6, lane = tid & 63, l15 = lane & 15, g = lane >> 4;
    f32x4 acc[2][12];
#pragma unroll
    for (int mf = 0; mf < 2; mf++)
#pragma unroll
        for (int f = 0; f < 12; f++) acc[mf][f] = (f32x4){0.f, 0.f, 0.f, 0.f};

    {   // stage step 0
        u16* ldsb = &wbuf[0][0] + (size_t)w * 64 * 8;
#pragma unroll
        for (int j = 0; j < 6; j++)
            gl_lds16(wqk + (size_t)(j * 256 + tid) * 8, ldsb + (size_t)j * 256 * 8);
    }
    __syncthreads();
    for (int s = 0; s < 27; s++) {
        const int cur = s & 1;
        if (s + 1 < 27) {   // prefetch next weight slice into other buffer
            const u16* src = wqk + (size_t)(s + 1) * 12288;
            u16* ldsb = &wbuf[cur ^ 1][0] + (size_t)w * 64 * 8;
#pragma unroll
            for (int j = 0; j < 6; j++)
                gl_lds16(src + (size_t)(j * 256 + tid) * 8, ldsb + (size_t)j * 256 * 8);
        }
        const int cic = s / 9, tap = s - cic * 9;
        const int dy = tap / 3 - 1, dx = tap - (tap / 3) * 3 - 1;
        const int ci0 = cic * 32 + g * 8;
        size_t ab = ((size_t)(b * 130 + y + 1 + dy) * 130 + (w * 32 + l15 + 1 + dx)) * 96 + ci0;
        i32x4 ah0 = *(const i32x4*)(ph + ab);
        i32x4 ah1 = *(const i32x4*)(ph + ab + 16 * 96);
        i32x4 al0 = *(const i32x4*)(pl + ab);
        i32x4 al1 = *(const i32x4*)(pl + ab + 16 * 96);
#pragma unroll
        for (int f = 0; f < 12; f++) {
            i32x4 bh = *(const i32x4*)(&wbuf[cur][((0 + g) * 192 + f * 16 + l15) * 8]);
            i32x4 bl = *(const i32x4*)(&wbuf[cur][((4 + g) * 192 + f * 16 + l15) * 8]);
            acc[0][f] = mfma16(ah0, bh, acc[0][f]);
            acc[0][f] = mfma16(ah0, bl, acc[0][f]);
            acc[0][f] = mfma16(al0, bh, acc[0][f]);
            acc[1][f] = mfma16(ah1, bh, acc[1][f]);
            acc[1][f] = mfma16(ah1, bl, acc[1][f]);
            acc[1][f] = mfma16(al1, bh, acc[1][f]);
        }
        __syncthreads();
    }
#pragma unroll
    for (int f = 0; f < 12; f++) {
        const bool isQ = (f < 6);
        const int co = (isQ ? f : f - 6) * 16 + l15;
        const float bb = isQ ? bq[co] : bk[co];
        float* op = isQ ? fq : fk;
#pragma unroll
        for (int mf = 0; mf < 2; mf++) {
            const int xp = w * 32 + mf * 16 + g * 4;
#pragma unroll
            for (int r = 0; r < 4; r++)
                op[((size_t)((b * 128 + y) * 128 + xp + r)) * 96 + co] = acc[mf][f][r] + bb;
        }
    }
}

// ---- V conv, single bf16, same template ----
__global__ __launch_bounds__(256) void k_convv2(
        const u16* __restrict__ p2, const u16* __restrict__ wv,
        const float* __restrict__ bv, u16* __restrict__ fvb) {
    __shared__ u16 vbuf[2][3072];  // [g][co96][8] per buffer, 6KB each
    const int tid = threadIdx.x;
    const int b = blockIdx.x >> 7, y = blockIdx.x & 127;
    const int w = tid >> 6, lane = tid & 63, l15 = lane & 15, g = lane >> 4;
    f32x4 acc[2][6];
#pragma unroll
    for (int mf = 0; mf < 2; mf++)
#pragma unroll
        for (int f = 0; f < 6; f++) acc[mf][f] = (f32x4){0.f, 0.f, 0.f, 0.f};
    {
        gl_lds16(wv + (size_t)tid * 8, &vbuf[0][0] + (size_t)w * 64 * 8);
        if (w < 2)
            gl_lds16(wv + (size_t)(256 + tid) * 8, &vbuf[0][0] + (size_t)(256 + w * 64) * 8);
    }
    __syncthreads();
    for (int s = 0; s < 27; s++) {
        const int cur = s & 1;
        if (s + 1 < 27) {
            const u16* src = wv + (size_t)(s + 1) * 3072;
            gl_lds16(src + (size_t)tid * 8, &vbuf[cur ^ 1][0] + (size_t)w * 64 * 8);
            if (w < 2)
                gl_lds16(src + (size_t)(256 + tid) * 8, &vbuf[cur ^ 1][0] + (size_t)(256 + w * 64) * 8);
        }
        const int cic = s / 9, tap = s - cic * 9;
        const int dy = tap / 3 - 1, dx = tap - (tap / 3) * 3 - 1;
        const int ci0 = cic * 32 + g * 8;
        size_t ab = ((size_t)(b * 130 + y + 1 + dy) * 130 + (w * 32 + l15 + 1 + dx)) * 96 + ci0;
        i32x4 ah0 = *(const i32x4*)(p2 + ab);
        i32x4 ah1 = *(const i32x4*)(p2 + ab + 16 * 96);
#pragma unroll
        for (int f = 0; f < 6; f++) {
            i32x4 bfr = *(const i32x4*)(&vbuf[cur][(g * 96 + f * 16 + l15) * 8]);
            acc[0][f] = mfma16(ah0, bfr, acc[0][f]);
            acc[1][f] = mfma16(ah1, bfr, acc[1][f]);
        }
        __syncthreads();
    }
#pragma unroll
    for (int f = 0; f < 6; f++) {
        const int co = f * 16 + l15;
        const float bb = bv[co];
#pragma unroll
        for (int mf = 0; mf < 2; mf++) {
            const int xp = w * 32 + mf * 16 + g * 4;
#pragma unroll
            for (int r = 0; r < 4; r++)
                fvb[((size_t)((b * 128 + y) * 128 + xp + r)) * 96 + co] = f2bf(acc[mf][f][r] + bb);
        }
    }
}

// ---- per-patch: FK -> Ktilde = M B M (in place); F1W = A M B (bf16 NHWC) ----
// M = D^T D = 8I + 2*ones
__global__ __launch_bounds__(256) void k_patch(
        const float* __restrict__ fq, float* __restrict__ fk, u16* __restrict__ f1w) {
    int blk = blockIdx.x;
    int b = blk >> 6, py = (blk >> 1) & 31, xh = blk & 1;
    int y0 = py * 4;
    for (int it = 0; it < 6; it++) {
        int item = threadIdx.x + it * 256;
        int pxl = item / 96, c = item - pxl * 96;
        int x0 = (xh * 16 + pxl) * 4;
        float A[4][4], Bm[4][4];
        size_t rb[4];
#pragma unroll
        for (int r = 0; r < 4; r++) {
            rb[r] = ((size_t)((b * 128 + y0 + r) * 128 + x0)) * 96 + c;
#pragma unroll
            for (int m = 0; m < 4; m++) {
                A[r][m] = fq[rb[r] + (size_t)m * 96];
                Bm[r][m] = fk[rb[r] + (size_t)m * 96];
            }
        }
        float rsB[4], csB[4], rsA[4], tot = 0.f;
#pragma unroll
        for (int r = 0; r < 4; r++) {
            rsB[r] = Bm[r][0] + Bm[r][1] + Bm[r][2] + Bm[r][3];
            rsA[r] = A[r][0] + A[r][1] + A[r][2] + A[r][3];
            tot += rsB[r];
        }
#pragma unroll
        for (int m = 0; m < 4; m++) csB[m] = Bm[0][m] + Bm[1][m] + Bm[2][m] + Bm[3][m];
#pragma unroll
        for (int r = 0; r < 4; r++)
#pragma unroll
            for (int m = 0; m < 4; m++)
                fk[rb[r] + (size_t)m * 96] = 64.f * Bm[r][m] + 16.f * (rsB[r] + csB[m]) + 4.f * tot;
#pragma unroll
        for (int r = 0; r < 4; r++)
#pragma unroll
            for (int m = 0; m < 4; m++) {
                float ab = A[r][0] * Bm[0][m] + A[r][1] * Bm[1][m]
                         + A[r][2] * Bm[2][m] + A[r][3] * Bm[3][m];
                f1w[rb[r] + (size_t)m * 96] = f2bf(8.f * ab + 2.f * rsA[r] * csB[m]);
            }
    }
}

// ---- attn logits (fp32 inner, f64 master), PART f32 [B][64][96][96] ----
__global__ __launch_bounds__(256) void k_attn(
        const float* __restrict__ fq, const float* __restrict__ kt,
        float* __restrict__ part) {
    __shared__ float qs[96 * 65];
    __shared__ float ks[96 * 65];
    int b = blockIdx.x >> 6, s = blockIdx.x & 63;
    int l0 = s * 256;
    int tx = threadIdx.x & 15, ty = threadIdx.x >> 4;
    double accD[6][6];
#pragma unroll
    for (int a = 0; a < 6; a++)
#pragma unroll
        for (int bb = 0; bb < 6; bb++) accD[a][bb] = 0.0;
    for (int ch = 0; ch < 4; ch++) {
        __syncthreads();
        for (int idx = threadIdx.x; idx < 1536; idx += 256) {
            int p = idx / 24, c0 = (idx - p * 24) * 4;
            size_t off = ((size_t)b * 16384 + l0 + ch * 64 + p) * 96 + c0;
            f32x4 qv = *(const f32x4*)(fq + off);
            f32x4 kv = *(const f32x4*)(kt + off);
#pragma unroll
            for (int u = 0; u < 4; u++) {
                qs[(c0 + u) * 65 + p] = qv[u];
                ks[(c0 + u) * 65 + p] = kv[u];
            }
        }
        __syncthreads();
        float acc[6][6];
#pragma unroll
        for (int a = 0; a < 6; a++)
#pragma unroll
            for (int bb = 0; bb < 6; bb++) acc[a][bb] = 0.f;
        for (int l = 0; l < 64; l++) {
            float qv[6], kv[6];
#pragma unroll
            for (int a = 0; a < 6; a++) qv[a] = qs[(ty + 16 * a) * 65 + l];
#pragma unroll
            for (int bb = 0; bb < 6; bb++) kv[bb] = ks[(tx + 16 * bb) * 65 + l];
#pragma unroll
            for (int a = 0; a < 6; a++)
#pragma unroll
                for (int bb = 0; bb < 6; bb++) acc[a][bb] += qv[a] * kv[bb];
        }
#pragma unroll
        for (int a = 0; a < 6; a++)
#pragma unroll
            for (int bb = 0; bb < 6; bb++) accD[a][bb] += (double)acc[a][bb];
    }
#pragma unroll
    for (int a = 0; a < 6; a++)
#pragma unroll
        for (int bb = 0; bb < 6; bb++)
            part[((size_t)((b * 64 + s) * 96 + ty + 16 * a)) * 96 + tx + 16 * bb] = (float)accD[a][bb];
}

// ---- reduce split-K + temperature + row softmax -> bf16 weights ----
__global__ __launch_bounds__(128) void k_softmax(
        const float* __restrict__ part, const float* __restrict__ temp,
        u16* __restrict__ attnb) {
    __shared__ float red[128];
    int b = blockIdx.x / 96, i2 = blockIdx.x - b * 96;
    int j2 = threadIdx.x;
    float v = 0.f;
    if (j2 < 96) {
        for (int s = 0; s < 64; s++)
            v += part[((size_t)((b * 64 + s) * 96 + i2)) * 96 + j2];
        v *= temp[0];
    }
    red[j2] = (j2 < 96) ? v : -3.4e38f;
    __syncthreads();
    for (int off = 64; off >= 1; off >>= 1) {
        if (j2 < off) red[j2] = fmaxf(red[j2], red[j2 + off]);
        __syncthreads();
    }
    float mx = red[0];
    __syncthreads();
    float e = (j2 < 96) ? expf(v - mx) : 0.f;
    red[j2] = e;
    __syncthreads();
    for (int off = 64; off >= 1; off >>= 1) {
        if (j2 < off) red[j2] += red[j2 + off];
        __syncthreads();
    }
    float sum = red[0];
    if (j2 < 96) attnb[((size_t)(b * 96) + i2) * 96 + j2] = f2bf(e / sum);
}

// ---- Gt = (F_Q - 0.5 F_V)^T, Fvn = F_V, both bf16 [B][C][.][.] ----
__global__ __launch_bounds__(256) void k_gprep(
        const float* __restrict__ fqn, const u16* __restrict__ fvb,
        u16* __restrict__ gt, u16* __restrict__ fvn) {
    __shared__ u16 lg[8 * 32 * 33];
    __shared__ u16 lv[8 * 32 * 33];
    int blk = blockIdx.x;
    int b = blk / 192;
    int r = blk - b * 192;
    int yt = r / 48; r -= yt * 48;
    int xt = r / 12; int cc = r - xt * 12;
    int y0 = yt * 32, x0 = xt * 32, c0 = cc * 8;
    for (int idx = threadIdx.x; idx < 8192; idx += 256) {
        int pix = idx >> 3, cl = idx & 7;
        int yy = pix >> 5, xx = pix & 31;
        size_t off = ((size_t)((b * 128 + y0 + yy) * 128 + x0 + xx)) * 96 + c0 + cl;
        float q = fqn[off];
        float v = bf2f(fvb[off]);
        int la = (cl * 32 + yy) * 33 + xx;
        lg[la] = f2bf(q - 0.5f * v);
        lv[la] = f2bf(v);
    }
    __syncthreads();
    for (int idx = threadIdx.x; idx < 8192; idx += 256) {
        int yy = idx & 31, xl = (idx >> 5) & 31, cl = idx >> 10;
        gt[((size_t)((b * 96 + c0 + cl) * 128 + x0 + xl)) * 128 + y0 + yy] = lg[(cl * 32 + yy) * 33 + xl];
    }
    for (int idx = threadIdx.x; idx < 8192; idx += 256) {
        int xx = idx & 31, yl = (idx >> 5) & 31, cl = idx >> 10;
        fvn[((size_t)((b * 96 + c0 + cl) * 128 + y0 + yl)) * 128 + x0 + xx] = lv[(cl * 32 + yl) * 33 + xx];
    }
}

// ---- FCFR[b][i][pix] = sum_j attn[i][j] * F1W[b][pix][j]  (bf16 MFMA) ----
__global__ __launch_bounds__(256) void k_fcfr2(
        const u16* __restrict__ attnb, const u16* __restrict__ f1w,
        u16* __restrict__ fc) {
    int b = blockIdx.x >> 6, pc = blockIdx.x & 63;
    int lane = threadIdx.x & 63, wv_ = threadIdx.x >> 6;
    int l15 = lane & 15, g = lane >> 4;
    int pbase = pc * 256 + wv_ * 64;
    f32x4 acc[6][4];
#pragma unroll
    for (int m = 0; m < 6; m++)
#pragma unroll
        for (int n = 0; n < 4; n++) acc[m][n] = (f32x4){0.f, 0.f, 0.f, 0.f};
#pragma unroll
    for (int ks = 0; ks < 3; ks++) {
        int k0 = ks * 32 + g * 8;
        i32x4 afr[6];
#pragma unroll
        for (int m = 0; m < 6; m++)
            afr[m] = *(const i32x4*)(attnb + ((size_t)(b * 96 + m * 16 + l15)) * 96 + k0);
#pragma unroll
        for (int n = 0; n < 4; n++) {
            i32x4 bfr = *(const i32x4*)(f1w + ((size_t)(b * 16384 + pbase + n * 16 + l15)) * 96 + k0);
#pragma unroll
            for (int m = 0; m < 6; m++)
                acc[m][n] = mfma16(afr[m], bfr, acc[m][n]);
        }
    }
#pragma unroll
    for (int m = 0; m < 6; m++)
#pragma unroll
        for (int n = 0; n < 4; n++)
#pragma unroll
            for (int r = 0; r < 4; r++) {
                int i2 = m * 16 + g * 4 + r;
                int pix = pbase + n * 16 + l15;
                fc[((size_t)(b * 96 + i2)) * HWSZ + pix] = f2bf(acc[m][n][r]);
            }
}

// ---- out = Fcfrout @ (F_Q - 0.5 F_V) + F_V  (bf16 MFMA, per (b,c) 128^3) ----
__global__ __launch_bounds__(256) void k_final(
        const u16* __restrict__ fc, const u16* __restrict__ gt,
        const u16* __restrict__ fvn, float* __restrict__ out) {
    int b = blockIdx.x / 96, c = blockIdx.x - b * 96;
    int lane = threadIdx.x & 63, wv_ = threadIdx.x >> 6;
    int l15 = lane & 15, g = lane >> 4;
    const u16* A = fc + ((size_t)(b * 96 + c)) * HWSZ;
    const u16* Bm = gt + ((size_t)(b * 96 + c)) * HWSZ;
    f32x4 acc[2][8];
#pragma unroll
    for (int mf = 0; mf < 2; mf++)
#pragma unroll
        for (int nf = 0; nf < 8; nf++) acc[mf][nf] = (f32x4){0.f, 0.f, 0.f, 0.f};
#pragma unroll
    for (int kc = 0; kc < 4; kc++) {
        int k0 = kc * 32 + g * 8;
        i32x4 af[2];
#pragma unroll
        for (int mf = 0; mf < 2; mf++)
            af[mf] = *(const i32x4*)(A + (size_t)(wv_ * 32 + mf * 16 + l15) * 128 + k0);
#pragma unroll
        for (int nf = 0; nf < 8; nf++) {
            i32x4 bf = *(const i32x4*)(Bm + (size_t)(nf * 16 + l15) * 128 + k0);
#pragma unroll
            for (int mf = 0; mf < 2; mf++)
                acc[mf][nf] = mfma16(af[mf], bf, acc[mf][nf]);
        }
    }
    const u16* V = fvn + ((size_t)(b * 96 + c)) * HWSZ;
    float* O = out + ((size_t)(b * 96 + c)) * HWSZ;
#pragma unroll
    for (int mf = 0; mf < 2; mf++)
#pragma unroll
        for (int nf = 0; nf < 8; nf++)
#pragma unroll
            for (int r = 0; r < 4; r++) {
                int y = wv_ * 32 + mf * 16 + g * 4 + r;
                int x = nf * 16 + l15;
                O[y * 128 + x] = acc[mf][nf][r] + bf2f(V[y * 128 + x]);
            }
}

extern "C" void kernel_launch(void* const* d_in, const int* in_sizes, int n_in,
                              void* d_out, int out_size, void* d_ws, size_t ws_size,
                              hipStream_t stream) {
    (void)in_sizes; (void)n_in;
    if (ws_size < (size_t)WS_NEED) {
        k_diag<<<2048, 256, 0, stream>>>((float*)d_out, out_size, (float)(ws_size >> 10));
        return;
    }
    const float* in1 = (const float*)d_in[0];
    const float* in2 = (const float*)d_in[1];
    const float* wq  = (const float*)d_in[2];
    const float* bq  = (const float*)d_in[3];
    const float* wk  = (const float*)d_in[4];
    const float* bk  = (const float*)d_in[5];
    const float* wv  = (const float*)d_in[6];
    const float* bv  = (const float*)d_in[7];
    const float* temp = (const float*)d_in[8];
    char* ws = (char*)d_ws;
    float* FQ   = (float*)(ws + OFF_FQ);
    float* FK   = (float*)(ws + OFF_FK);
    u16*  GT    = (u16*)(ws + OFF_GT);
    u16*  FVN   = (u16*)(ws + OFF_FVN);
    u16*  PAD1H = (u16*)(ws + OFF_PAD1H);
    u16*  PAD1L = (u16*)(ws + OFF_PAD1L);
    u16*  PAD2  = (u16*)(ws + OFF_PAD2);
    u16*  F1W   = (u16*)(ws + OFF_F1W);
    float* PART = (float*)(ws + OFF_PART);
    u16*  FCFR  = (u16*)(ws + OFF_FCFR);
    u16*  FVB   = (u16*)(ws + OFF_FVB);
    u16*  ATTNB = (u16*)(ws + OFF_ATTNB);
    u16*  WQK   = (u16*)(ws + OFF_WQK);
    u16*  WV    = (u16*)(ws + OFF_WV);

    k_zhalo<<<24, 256, 0, stream>>>(PAD1H);   // PAD1H,PAD1L,PAD2 contiguous: 24 images
    k_trans_split<<<1024, 256, 0, stream>>>(in1, PAD1H, PAD1L);
    k_trans_split<<<1024, 256, 0, stream>>>(in2, PAD2, nullptr);
    k_weights_qk<<<192, 128, 0, stream>>>(wq, wk, WQK);
    k_weights_v<<<96, 128, 0, stream>>>(wv, WV);
    k_convqk2<<<1024, 256, 0, stream>>>(PAD1H, PAD1L, WQK, bq, bk, FQ, FK);
    k_convv2<<<1024, 256, 0, stream>>>(PAD2, WV, bv, FVB);
    k_patch<<<512, 256, 0, stream>>>(FQ, FK, F1W);       // FK -> Ktilde; F1W over PAD1H (dead)
    k_attn<<<512, 256, 0, stream>>>(FQ, FK, PART);       // PART over PAD1L (dead)
    k_softmax<<<768, 128, 0, stream>>>(PART, temp, ATTNB);
    k_gprep<<<1536, 256, 0, stream>>>(FQ, FVB, GT, FVN); // GT/FVN over FK (dead after attn)
    k_fcfr2<<<512, 256, 0, stream>>>(ATTNB, F1W, FCFR);  // FCFR over PAD2 (dead)
    k_final<<<768, 256, 0, stream>>>(FCFR, GT, FVN, (float*)d_out);
}